// Round 6
// baseline (433.209 us; speedup 1.0000x reference)
//
#include <hip/hip_runtime.h>

#define N_NODES 50000
#define N_EDGES 800000
#define R_REL   8
#define NR      (N_NODES * R_REL)        // 400000
#define SCAN_CHUNK 2048
#define SCAN_NBLK  ((NR + SCAN_CHUNK - 1) / SCAN_CHUNK)   // 196

typedef float  f32x4  __attribute__((ext_vector_type(4)));
typedef __bf16 bf16x8 __attribute__((ext_vector_type(8)));

__device__ __forceinline__ unsigned short f2bf(float f) {
    unsigned int u = __float_as_uint(f);
    u = (u + 0x7FFFu + ((u >> 16) & 1u)) >> 16;   // RNE
    return (unsigned short)u;
}
__device__ __forceinline__ float bflo(unsigned int u) { return __uint_as_float(u << 16); }
__device__ __forceinline__ float bfhi(unsigned int u) { return __uint_as_float(u & 0xFFFF0000u); }

__device__ __forceinline__ void acc16(float* a, uint4 u0, uint4 u1) {
    a[0]  += bflo(u0.x);   a[1]  += bfhi(u0.x);
    a[2]  += bflo(u0.y);   a[3]  += bfhi(u0.y);
    a[4]  += bflo(u0.z);   a[5]  += bfhi(u0.z);
    a[6]  += bflo(u0.w);   a[7]  += bfhi(u0.w);
    a[8]  += bflo(u1.x);   a[9]  += bfhi(u1.x);
    a[10] += bflo(u1.y);   a[11] += bfhi(u1.y);
    a[12] += bflo(u1.z);   a[13] += bfhi(u1.z);
    a[14] += bflo(u1.w);   a[15] += bfhi(u1.w);
}

// ---------------- CSR build ----------------

__global__ void k_hist(const int* __restrict__ dst, const int* __restrict__ et,
                       int* __restrict__ cnt) {
    int e = blockIdx.x * 256 + threadIdx.x;
    if (e < N_EDGES) atomicAdd(&cnt[dst[e] * R_REL + et[e]], 1);
}

__global__ void k_scan1(const int* __restrict__ cnt, int* __restrict__ offs,
                        int* __restrict__ bsum) {
    __shared__ int sd[256];
    int t = threadIdx.x;
    int base = blockIdx.x * SCAN_CHUNK + t * 8;
    int v[8];
    int tot = 0;
#pragma unroll
    for (int i = 0; i < 8; i++) {
        int idx = base + i;
        int xv = (idx < NR) ? cnt[idx] : 0;
        v[i] = tot;
        tot += xv;
    }
    sd[t] = tot;
    __syncthreads();
    for (int off = 1; off < 256; off <<= 1) {
        int y = (t >= off) ? sd[t - off] : 0;
        __syncthreads();
        sd[t] += y;
        __syncthreads();
    }
    int excl = sd[t] - tot;
#pragma unroll
    for (int i = 0; i < 8; i++) {
        int idx = base + i;
        if (idx < NR) offs[idx] = v[i] + excl;
    }
    if (t == 255) bsum[blockIdx.x] = sd[255];
}

__global__ void k_scan2(const int* __restrict__ bsum, int* __restrict__ bsum2) {
    __shared__ int sd[256];
    int t = threadIdx.x;
    int v = (t < SCAN_NBLK) ? bsum[t] : 0;
    sd[t] = v;
    __syncthreads();
    for (int off = 1; off < 256; off <<= 1) {
        int y = (t >= off) ? sd[t - off] : 0;
        __syncthreads();
        sd[t] += y;
        __syncthreads();
    }
    bsum2[t] = sd[t] - v;
}

__global__ void k_scan3(int* __restrict__ offs, const int* __restrict__ bsum2,
                        int* __restrict__ cursor) {
    int t = threadIdx.x;
    int b = blockIdx.x;
    int add = bsum2[b];
    int base = b * SCAN_CHUNK + t * 8;
#pragma unroll
    for (int i = 0; i < 8; i++) {
        int idx = base + i;
        if (idx < NR) {
            int v = offs[idx] + add;
            offs[idx] = v;
            cursor[idx] = v;
        }
    }
    if (b == 0 && t == 0) offs[NR] = N_EDGES;
}

__global__ void k_scatter(const int* __restrict__ src, const int* __restrict__ dst,
                          const int* __restrict__ et, int* __restrict__ cursor,
                          int* __restrict__ srcS) {
    int e = blockIdx.x * 256 + threadIdx.x;
    if (e < N_EDGES) {
        int pos = atomicAdd(&cursor[dst[e] * R_REL + et[e]], 1);
        srcS[pos] = src[e];
    }
}

// ---------------- converts ----------------

__global__ void k_cvt_x(const float* __restrict__ x, unsigned short* __restrict__ xb, int n4) {
    int i = blockIdx.x * 256 + threadIdx.x;
    if (i < n4) {
        float4 v = *(const float4*)(x + (size_t)i * 4);
        ushort4 o;
        o.x = f2bf(v.x); o.y = f2bf(v.y); o.z = f2bf(v.z); o.w = f2bf(v.w);
        *(ushort4*)(xb + (size_t)i * 4) = o;
    }
}

// Both layers' weights in one launch.
// Wt[seg][n][k] bf16, seg0 = root, segs 1..8 = W[r]. Input root[k][n], W[r][k][n].
#define W1_ELEMS (9 * 128 * 128)
#define W2_ELEMS (9 * 64 * 128)
__global__ void k_wprep_all(const float* __restrict__ root1, const float* __restrict__ W1,
                            const float* __restrict__ root2, const float* __restrict__ W2,
                            unsigned short* __restrict__ Wt1, unsigned short* __restrict__ Wt2) {
    int idx = blockIdx.x * 256 + threadIdx.x;
    if (idx < W1_ELEMS) {
        int k = idx & 127;
        int rest = idx >> 7;       // seg*128 + n
        int n = rest & 127;
        int seg = rest >> 7;
        float v = (seg == 0) ? root1[k * 128 + n] : W1[((seg - 1) * 128 + k) * 128 + n];
        Wt1[idx] = f2bf(v);
    } else if (idx < W1_ELEMS + W2_ELEMS) {
        int j = idx - W1_ELEMS;
        int k = j & 127;
        int rest = j >> 7;         // seg*64 + n
        int n = rest & 63;
        int seg = rest >> 6;
        float v = (seg == 0) ? root2[k * 64 + n] : W2[((seg - 1) * 128 + k) * 64 + n];
        Wt2[j] = f2bf(v);
    }
}

// ---------------- fused aggregate + MFMA GEMM layer ----------------
// Block = 256 threads (4 waves), 16-node tile; 50000/16 = 3125 blocks exactly
// (no tail -> no guards anywhere).
// Gather item = (node, rel, 64-feat half): 16*8*2 = 256 -> each thread walks
// exactly ONE edge chain; all 256 chains independent. One straggler wait per
// block (vs 9 barrier-coupled waits in the per-seg structure).
// Root term: MFMA directly from global xb rows (dense, L2-resident).
// MFMA split: all waves use rows 0..15; wave w owns col-tiles nb0=w*NBW.

template <int FOUT, bool RELU, bool OUT_BF16>
__global__ __launch_bounds__(256, 2) void k_layer(
    const unsigned short* __restrict__ xb,   // [N,128] bf16
    const unsigned short* __restrict__ Wt,   // [9,FOUT,128] bf16
    const float* __restrict__ bias,          // [FOUT] fp32
    const int* __restrict__ offs,            // [NR+1]
    const int* __restrict__ srcS,            // [E]
    unsigned short* __restrict__ outb,       // [N,FOUT] bf16 (if OUT_BF16)
    float* __restrict__ outf)                // [N,FOUT] fp32 (else)
{
    constexpr int NBW = FOUT / 64;           // col-tiles per wave: 2 (L1) or 1 (L2)
    __shared__ __align__(16) unsigned short As[8][16][136];

    const int t = threadIdx.x;
    const int node0 = blockIdx.x * 16;
    // gather mapping: pairs (t, t+1) share an edge list -> adjacent 128B halves coalesce
    const int g_nl  = t >> 4;        // local node 0..15
    const int g_rel = (t >> 1) & 7;  // relation 0..7
    const int g_sl  = t & 1;         // 64-feat half
    // mfma mapping
    const int lane = t & 63;
    const int w = t >> 6;            // wave 0..3
    const int quad = lane >> 4;
    const int tc = lane & 15;
    const int nb0 = w * NBW;

    f32x4 acc[NBW];
#pragma unroll
    for (int nb = 0; nb < NBW; ++nb) acc[nb] = (f32x4){0.f, 0.f, 0.f, 0.f};

    // ---- gather: ONE chain per thread ----
    {
        const int idx = (node0 + g_nl) * 8 + g_rel;
        const int beg = offs[idx];
        const int end = offs[idx + 1];
        const int deg = end - beg;
        const unsigned short* bx = xb + g_sl * 64;
        float a[64];
#pragma unroll
        for (int i = 0; i < 64; ++i) a[i] = 0.f;
        for (int j = beg; j < end; ++j) {
            int s = srcS[j];
            const uint4* p = (const uint4*)(bx + (size_t)s * 128);
            uint4 v0 = p[0], v1 = p[1], v2 = p[2], v3 = p[3];
            uint4 v4 = p[4], v5 = p[5], v6 = p[6], v7 = p[7];
            acc16(a,      v0, v1);
            acc16(a + 16, v2, v3);
            acc16(a + 32, v4, v5);
            acc16(a + 48, v6, v7);
        }
        float scl = 1.f / (float)(deg > 1 ? deg : 1);
        unsigned int pk[32];
#pragma unroll
        for (int i = 0; i < 32; ++i)
            pk[i] = (unsigned int)f2bf(a[i * 2] * scl) |
                    ((unsigned int)f2bf(a[i * 2 + 1] * scl) << 16);
        uint4* d = (uint4*)&As[g_rel][g_nl][g_sl * 64];
#pragma unroll
        for (int i = 0; i < 8; ++i)
            d[i] = make_uint4(pk[i * 4], pk[i * 4 + 1], pk[i * 4 + 2], pk[i * 4 + 3]);
    }

    // ---- root-term MFMA from global xb (overlaps other waves' gather tails) ----
    {
        const unsigned short* Ag = xb + (size_t)(node0 + tc) * 128 + quad * 8;
        const unsigned short* Bb = Wt + quad * 8;   // seg 0
#pragma unroll
        for (int kk = 0; kk < 4; ++kk) {
            bf16x8 af = *(const bf16x8*)(Ag + kk * 32);
#pragma unroll
            for (int nb = 0; nb < NBW; ++nb) {
                bf16x8 bf = *(const bf16x8*)(Bb + ((nb0 + nb) * 16 + tc) * 128 + kk * 32);
                acc[nb] = __builtin_amdgcn_mfma_f32_16x16x32_bf16(af, bf, acc[nb], 0, 0, 0);
            }
        }
    }

    __syncthreads();   // As fully written

    // ---- relation MFMAs from LDS ----
#pragma unroll
    for (int ss = 0; ss < 8; ++ss) {
        const unsigned short* Arow = &As[ss][tc][0];
        const unsigned short* Bb = Wt + (size_t)(ss + 1) * FOUT * 128 + quad * 8;
#pragma unroll
        for (int kk = 0; kk < 4; ++kk) {
            bf16x8 af = *(const bf16x8*)(Arow + kk * 32 + quad * 8);
#pragma unroll
            for (int nb = 0; nb < NBW; ++nb) {
                bf16x8 bf = *(const bf16x8*)(Bb + ((nb0 + nb) * 16 + tc) * 128 + kk * 32);
                acc[nb] = __builtin_amdgcn_mfma_f32_16x16x32_bf16(af, bf, acc[nb], 0, 0, 0);
            }
        }
    }

    // epilogue: D layout col = lane&15, row = quad*4 + reg
#pragma unroll
    for (int nb = 0; nb < NBW; ++nb) {
        int col = (nb0 + nb) * 16 + tc;
        float bs = bias[col];
#pragma unroll
        for (int i = 0; i < 4; ++i) {
            int r = node0 + quad * 4 + i;
            float v = acc[nb][i] + bs;
            if (RELU) v = fmaxf(v, 0.f);
            if (OUT_BF16) outb[(size_t)r * FOUT + col] = f2bf(v);
            else          outf[(size_t)r * FOUT + col] = v;
        }
    }
}

// ---------------- launch ----------------

extern "C" void kernel_launch(void* const* d_in, const int* in_sizes, int n_in,
                              void* d_out, int out_size, void* d_ws, size_t ws_size,
                              hipStream_t stream) {
    const float* x     = (const float*)d_in[0];
    const int*   ei    = (const int*)d_in[1];  // [2][E]: row0=src, row1=dst
    const int*   et    = (const int*)d_in[2];  // [E]
    const float* W1    = (const float*)d_in[3];
    const float* root1 = (const float*)d_in[4];
    const float* b1    = (const float*)d_in[5];
    const float* W2    = (const float*)d_in[6];
    const float* root2 = (const float*)d_in[7];
    const float* b2    = (const float*)d_in[8];
    float* out = (float*)d_out;

    int* ws     = (int*)d_ws;
    int* cnt    = ws;                  // NR  (reused for Wt1 after scans)
    int* offs   = cnt + NR;            // NR+1 (padded to NR+128)
    int* cursor = offs + NR + 128;     // NR  (reused for Wt2 after scatter)
    int* bsum   = cursor + NR;         // 256
    int* bsum2  = bsum + 256;          // 256
    int* srcS   = bsum2 + 256;         // E
    unsigned short* xb = (unsigned short*)(srcS + N_EDGES);  // [N,128] bf16
    unsigned short* hb = xb + (size_t)N_NODES * 128;         // [N,128] bf16
    unsigned short* Wt1 = (unsigned short*)cnt;              // 288 KB < 1.6 MB
    unsigned short* Wt2 = (unsigned short*)cursor;           // 144 KB < 1.6 MB

    hipMemsetAsync(cnt, 0, NR * sizeof(int), stream);
    k_hist<<<(N_EDGES + 255) / 256, 256, 0, stream>>>(ei + N_EDGES, et, cnt);
    k_scan1<<<SCAN_NBLK, 256, 0, stream>>>(cnt, offs, bsum);
    k_scan2<<<1, 256, 0, stream>>>(bsum, bsum2);
    k_scan3<<<SCAN_NBLK, 256, 0, stream>>>(offs, bsum2, cursor);
    k_scatter<<<(N_EDGES + 255) / 256, 256, 0, stream>>>(ei, ei + N_EDGES, et, cursor, srcS);

    // cnt dead after k_scan1, cursor dead after k_scatter -> safe to overwrite now
    k_wprep_all<<<(W1_ELEMS + W2_ELEMS + 255) / 256, 256, 0, stream>>>(
        root1, W1, root2, W2, Wt1, Wt2);
    k_cvt_x<<<(N_NODES * 32 + 255) / 256, 256, 0, stream>>>(x, xb, N_NODES * 32);

    const int NT = N_NODES / 16;  // 3125 exactly
    k_layer<128, true,  true ><<<NT, 256, 0, stream>>>(xb, Wt1, b1, offs, srcS, hb, nullptr);
    k_layer<64,  false, false><<<NT, 256, 0, stream>>>(hb, Wt2, b2, offs, srcS, nullptr, out);
}